// Round 10
// baseline (190.306 us; speedup 1.0000x reference)
//
#include <hip/hip_runtime.h>

#define SEQ    8192
#define S_TILE 180            // valid output positions per tile (192 computed - 12 shrink)
#define NROW   198            // staged input rows (192 + halo 6)
#define CS     1608           // chunk stride in halves; dwords=804 == 4 mod 32 (bank skew); holds 201 rows
#define NTHR   512            // 8 waves: waves 0-3 image 0, waves 4-7 image 1; wave owns 3 n-tiles
#define NREC   37             // 36 conv A-records + 1 MLP record (each 64 lanes x 16B = 1KB)
#define BN_HALFOFF (NREC*512) // float area offset (in halves) inside d_ws

typedef __attribute__((ext_vector_type(8))) _Float16 half8;
typedef __attribute__((ext_vector_type(4))) _Float16 half4v;
typedef __attribute__((ext_vector_type(4))) float    f32x4;

__device__ __forceinline__ int uni(int v){ return __builtin_amdgcn_readfirstlane(v); }

// ---------------- prep ----------------
// A-records carry the PREVIOUS layer's BN scale folded in: rec = W[co][ci][tap]*s_prev[ci].
// Stored activations are r = relu(z + bias'); BN of a layer is applied by the next
// layer's folded weights. bias'_L = b_L + sum_{ci,tap} W_L*t_{L-1}[ci]; at seq-OOB
// positions we store c_L = -t_L/s_L so the next layer's folded math sees exactly 0.
// fw1 folds s3; fb1' absorbs t3. Float area: [4][32]{bias', oob_const} then fb1'[16].
// Record (tap, mh): lane l holds A[m][k] = W'[co=mh*16+(l&15)][ci=(l>>4)*8+j][tap]
// (A-operand layout for mfma_f32_16x16x32: A[m=lane&15][k=quad*8+j]).
extern "C" __global__ void prep_kernel(
    const float* w0, const float* w1, const float* w2, const float* w3,
    const float* b0, const float* g0, const float* bb0, const float* rm0, const float* rv0,
    const float* b1, const float* g1, const float* bb1, const float* rm1, const float* rv1,
    const float* b2, const float* g2, const float* bb2, const float* rm2, const float* rv2,
    const float* b3, const float* g3, const float* bb3, const float* rm3, const float* rv3,
    const float* fw1, const float* fb1, _Float16* ws)
{
    const int tid = threadIdx.x;
    const int rec = blockIdx.x;
    if (rec < NREC) {
        if (tid < 64) {
            const int lane = tid;
            const float* W; const float *gp = nullptr, *rvp = nullptr; int CIN, K, r2;
            if      (rec < 6)  { W = w0;  CIN = 4;  K = 3; r2 = rec;      }
            else if (rec < 12) { W = w1;  CIN = 32; K = 3; r2 = rec - 6;  gp = g0; rvp = rv0; }
            else if (rec < 22) { W = w2;  CIN = 32; K = 5; r2 = rec - 12; gp = g1; rvp = rv1; }
            else if (rec < 36) { W = w3;  CIN = 32; K = 7; r2 = rec - 22; gp = g2; rvp = rv2; }
            else               { W = fw1; CIN = 32; K = 1; r2 = 0;        gp = g3; rvp = rv3; }
            int tap = r2 >> 1, mh = r2 & 1;
            int co  = mh*16 + (lane & 15);
            int ci0 = (lane >> 4) * 8;
            half8 h;
#pragma unroll
            for (int j = 0; j < 8; ++j) {
                int ci = ci0 + j;
                float wv = (ci < CIN) ? W[(co*CIN + ci)*K + tap] : 0.0f;
                if (gp) wv *= gp[ci & 31] * rsqrtf(rvp[ci & 31] + 1e-5f);  // s_prev
                h[j] = (_Float16)wv;
            }
            *(half8*)(ws + rec*512 + lane*8) = h;
        }
    } else {
        float* fa = (float*)(ws + BN_HALFOFF);
        if (tid < 128) {
            int l = tid >> 5, co = tid & 31;
            const float *g, *bb, *rm, *rv, *bi, *W = nullptr;
            const float *gp, *bbp, *rmp, *rvp; int K = 0;
            if      (l == 0) { g=g0; bb=bb0; rm=rm0; rv=rv0; bi=b0; gp=bbp=rmp=rvp=nullptr; }
            else if (l == 1) { g=g1; bb=bb1; rm=rm1; rv=rv1; bi=b1; W=w1; K=3; gp=g0; bbp=bb0; rmp=rm0; rvp=rv0; }
            else if (l == 2) { g=g2; bb=bb2; rm=rm2; rv=rv2; bi=b2; W=w2; K=5; gp=g1; bbp=bb1; rmp=rm1; rvp=rv1; }
            else             { g=g3; bb=bb3; rm=rm3; rv=rv3; bi=b3; W=w3; K=7; gp=g2; bbp=bb2; rmp=rm2; rvp=rv2; }
            float s = g[co] * rsqrtf(rv[co] + 1e-5f);
            float t = bb[co] - rm[co]*s;
            float bias = bi[co];
            if (l > 0) {
                for (int ci = 0; ci < 32; ++ci) {
                    float sp = gp[ci] * rsqrtf(rvp[ci] + 1e-5f);
                    float tp = bbp[ci] - rmp[ci]*sp;
                    float wsum = 0.f;
                    for (int tap = 0; tap < K; ++tap) wsum += W[(co*32 + ci)*K + tap];
                    bias += wsum * tp;
                }
            }
            fa[(l*32 + co)*2 + 0] = bias;
            fa[(l*32 + co)*2 + 1] = -t / s;    // stored value at seq-OOB output positions
        } else if (tid < 144) {
            int hh = tid - 128;
            float acc = fb1[hh];
            for (int c = 0; c < 32; ++c) {
                float s3 = g3[c] * rsqrtf(rv3[c] + 1e-5f);
                float t3 = bb3[c] - rm3[c]*s3;
                acc += fw1[hh*32 + c] * t3;
            }
            fa[256 + hh] = acc;                // fb1'
        }
    }
}

// ---------------- one conv layer via MFMA ----------------
// in/out: LDS f16, 4 chunks x rows x 8 halves (chunk cb holds ci 8cb..8cb+7).
// B-frag (lane l): pos = base+(l&15)+tap, ci = (l>>4)*8+j -> one b128 at q*CS + pos*8.
// D (C/D layout): col=lane&15 -> pos, row=q*4+r -> co (within m-half).
// BC0 (layer 0): A-records zero for ci>=8 -> all quads read chunk 0 (broadcast).
// Epilogue (BN folded forward): r = relu(acc + bias'); seq-OOB -> per-co const.
template<int K, int DOFF, bool BC0>
__device__ __forceinline__ void conv_layer(
    const _Float16* __restrict__ rec, const float2* __restrict__ bo,
    const _Float16* in, _Float16* outb, int s0, int ntb, int lane)
{
    const int q = lane >> 4, n = lane & 15;
    const _Float16* bbase = in + (BC0 ? 0 : q*CS) + (ntb*16 + n)*8;

    f32x4 acc[3][2];
#pragma unroll
    for (int nt = 0; nt < 3; ++nt)
#pragma unroll
        for (int mh = 0; mh < 2; ++mh) acc[nt][mh] = (f32x4){0.f, 0.f, 0.f, 0.f};

#pragma unroll
    for (int tap = 0; tap < K; ++tap) {
        half8 a0 = *(const half8*)(rec + (tap*2 + 0)*512 + lane*8);
        half8 a1 = *(const half8*)(rec + (tap*2 + 1)*512 + lane*8);
#pragma unroll
        for (int nt = 0; nt < 3; ++nt) {
            half8 bf = *(const half8*)(bbase + nt*128 + tap*8);
            acc[nt][0] = __builtin_amdgcn_mfma_f32_16x16x32_f16(a0, bf, acc[nt][0], 0, 0, 0);
            acc[nt][1] = __builtin_amdgcn_mfma_f32_16x16x32_f16(a1, bf, acc[nt][1], 0, 0, 0);
        }
    }

#pragma unroll
    for (int nt = 0; nt < 3; ++nt) {
        int pos = (ntb + nt)*16 + n;
        bool oob = (unsigned)(s0 + DOFF + pos) >= SEQ;
#pragma unroll
        for (int mh = 0; mh < 2; ++mh) {
            int co0 = mh*16 + q*4;
            half4v hv;
#pragma unroll
            for (int r = 0; r < 4; ++r) {
                float2 p = bo[co0 + r];   // x=bias' y=oob-const
                float v = fmaxf(acc[nt][mh][r] + p.x, 0.0f);
                if (oob) v = p.y;
                hv[r] = (_Float16)v;
            }
            int cb = mh*2 + (q >> 1);
            *(half4v*)(outb + cb*CS + pos*8 + (q & 1)*4) = hv;
        }
    }
}

extern "C" __global__ void __launch_bounds__(NTHR, 6)
dnashape_mfma(const float* __restrict__ x, const _Float16* __restrict__ ws,
              const float* __restrict__ fw2, const float* __restrict__ fb2,
              float* __restrict__ out)
{
    // Two images per block: halves the barrier instances per element vs R9.
    __shared__ _Float16 bufA[2][4*CS];
    __shared__ _Float16 bufB[2][4*CS];   // 51.4 KB -> 3 blocks/CU (24 waves, 75%)

    const int tid  = threadIdx.x;
    const int tile = blockIdx.x;
    const int s0   = tile * S_TILE;
    const int b0i  = blockIdx.y * 2;

    // Stage both images' chunk 0: f16(x[ci 0..3]) + 4 zero-halves (threads 0-255 -> img 0).
    const int timg = tid >> 8;
    {
        const float* xb = x + (b0i + timg)*4*SEQ;
        for (int li = (tid & 255); li < NROW; li += 256) {
            int sg = s0 - 7 + li;   // input origin s0-7 (halo 7)
            bool ok = (unsigned)sg < SEQ;
            float v0 = ok ? xb[0*SEQ + sg] : 0.f;
            float v1 = ok ? xb[1*SEQ + sg] : 0.f;
            float v2 = ok ? xb[2*SEQ + sg] : 0.f;
            float v3 = ok ? xb[3*SEQ + sg] : 0.f;
            half8 h0 = {(_Float16)v0, (_Float16)v1, (_Float16)v2, (_Float16)v3, 0, 0, 0, 0};
            *(half8*)(&bufB[timg][0*CS + li*8]) = h0;
        }
        // Zero bufA halo rows 192..199 (read beyond computed range, written by none).
        const half8 z8 = {0,0,0,0,0,0,0,0};
        int u = tid & 255;
        if (u < 32) *(half8*)(&bufA[timg][(u >> 3)*CS + (192 + (u & 7))*8]) = z8;
    }
    __syncthreads();

    const int lane = tid & 63;
    const int wv   = uni(tid >> 6);
    const int img  = wv >> 2;               // waves 0-3 -> image 0, 4-7 -> image 1
    const int ntb  = (wv & 3) * 3;          // wave-uniform n-tile base
    const float*  fa = (const float*)(ws + BN_HALFOFF);
    const float2* bo = (const float2*)fa;

    // Buffer origins: in=s0-7, L0out=s0-6, L1out=s0-5, L2out=s0-3, L3out=s0.
    // Validity chain (valid final rows 0..179): L3 reads L2out <=185, L2 valid to 185
    // (reads L1out <=189), L1 valid to 189 (reads L0out <=191), L0 valid to 191
    // (reads staged <=193 < 198). Garbage beyond is provably never consumed.
    conv_layer<3, -6, true >(ws +  0*512, bo +  0, bufB[img], bufA[img], s0, ntb, lane);
    __syncthreads();
    conv_layer<3, -5, false>(ws +  6*512, bo + 32, bufA[img], bufB[img], s0, ntb, lane);
    __syncthreads();
    conv_layer<5, -3, false>(ws + 12*512, bo + 64, bufB[img], bufA[img], s0, ntb, lane);
    __syncthreads();
    conv_layer<7,  0, false>(ws + 22*512, bo + 96, bufA[img], bufB[img], s0, ntb, lane);
    __syncthreads();

    // MLP 32 -> 16 (relu) -> 1 (fw1*s3 and fb1' prefolded): one MFMA per n-tile.
    {
        const int q = lane >> 4, n = lane & 15;
        half8 am = *(const half8*)(ws + 36*512 + lane*8);
        float fb1v[4], fw2v[4];
#pragma unroll
        for (int r = 0; r < 4; ++r) { fb1v[r] = fa[256 + q*4 + r]; fw2v[r] = fw2[q*4 + r]; }
        float fb2v = fb2[0];
        const int b = b0i + img;
#pragma unroll
        for (int nt = 0; nt < 3; ++nt) {
            int pos = (ntb + nt)*16 + n;
            half8 bf = *(const half8*)(&bufB[img][q*CS + pos*8]);
            f32x4 d = {0.f, 0.f, 0.f, 0.f};
            d = __builtin_amdgcn_mfma_f32_16x16x32_f16(am, bf, d, 0, 0, 0);
            float part = 0.f;
#pragma unroll
            for (int r = 0; r < 4; ++r) part += fmaxf(d[r] + fb1v[r], 0.f)*fw2v[r];
            part += __shfl_xor(part, 16, 64);   // reduce across the 4 quads (h-blocks)
            part += __shfl_xor(part, 32, 64);
            if (lane < 16) {
                int g = s0 + pos;
                if (pos < S_TILE && g < SEQ) out[b*SEQ + g] = part + fb2v;
            }
        }
    }
}

extern "C" void kernel_launch(void* const* d_in, const int* in_sizes, int n_in,
                              void* d_out, int out_size, void* d_ws, size_t ws_size,
                              hipStream_t stream) {
    const float* p[29];
    for (int i = 0; i < 29; ++i) p[i] = (const float*)d_in[i];
    _Float16* ws = (_Float16*)d_ws;   // needs 37*1024 + 1088 = 38976 B

    prep_kernel<<<dim3(NREC + 1), 144, 0, stream>>>(
        p[1], p[7], p[13], p[19],
        p[2], p[3], p[4], p[5], p[6],
        p[8], p[9], p[10], p[11], p[12],
        p[14], p[15], p[16], p[17], p[18],
        p[20], p[21], p[22], p[23], p[24],
        p[25], p[26], ws);

    dim3 grid((SEQ + S_TILE - 1) / S_TILE, 64);   // 46 x 64, 2 images per block
    dnashape_mfma<<<grid, NTHR, 0, stream>>>(p[0], (const _Float16*)ws,
                                             p[27], p[28], (float*)d_out);
}

// Round 11
// 187.376 us; speedup vs baseline: 1.0156x; 1.0156x over previous
//
#include <hip/hip_runtime.h>

#define SEQ    8192
#define S_TILE 180            // valid output positions per tile (192 computed - 12 shrink)
#define CS     1608           // chunk stride in halves; holds 201 rows (192 + halo + pad)
#define NTHR   512            // 8 waves: waves 0-3 image 0, waves 4-7 image 1; wave owns 3 n-tiles
#define NREC   37             // 36 conv A-records + 1 MLP record (each 64 lanes x 16B = 1KB)
#define BN_HALFOFF (NREC*512) // float area offset (in halves) inside d_ws

typedef __attribute__((ext_vector_type(8))) _Float16 half8;
typedef __attribute__((ext_vector_type(4))) _Float16 half4v;
typedef __attribute__((ext_vector_type(4))) float    f32x4;

__device__ __forceinline__ int uni(int v){ return __builtin_amdgcn_readfirstlane(v); }

// Unrolled (compile-time K) bias fold: sum_ci (sum_tap W[co][ci][tap]) * t_prev[ci].
// Constant bounds -> full unroll -> independent pipelined loads (the R10 version used
// runtime K/W and serialized ~224 load-use chains ~= 20us on one wave).
template<int K>
__device__ __forceinline__ float fold_bias(const float* __restrict__ W, int co,
    const float* __restrict__ gp, const float* __restrict__ bbp,
    const float* __restrict__ rmp, const float* __restrict__ rvp)
{
    float acc = 0.f;
#pragma unroll
    for (int ci = 0; ci < 32; ++ci) {
        float sp = gp[ci] * rsqrtf(rvp[ci] + 1e-5f);
        float tp = bbp[ci] - rmp[ci]*sp;
        float wsum = 0.f;
#pragma unroll
        for (int tap = 0; tap < K; ++tap) wsum += W[(co*32 + ci)*K + tap];
        acc += wsum * tp;
    }
    return acc;
}

// ---------------- prep ----------------
// A-records carry the PREVIOUS layer's BN scale folded in: rec = W[co][ci][tap]*s_prev[ci].
// Stored activations are r = relu(z + bias'); BN applied by the next layer's folded
// weights. At seq-OOB positions store -t/s so the next layer's folded math sees 0.
// fw1 folds s3; fb1' absorbs t3. Float area: [4][32]{bias', oob_const} then fb1'[16].
// Record (tap, mh): lane l holds A[m][k] = W'[co=mh*16+(l&15)][ci=(l>>4)*8+j][tap]
// (A-operand layout for mfma_f32_16x16x32: A[m=lane&15][k=quad*8+j]).
extern "C" __global__ void prep_kernel(
    const float* w0, const float* w1, const float* w2, const float* w3,
    const float* b0, const float* g0, const float* bb0, const float* rm0, const float* rv0,
    const float* b1, const float* g1, const float* bb1, const float* rm1, const float* rv1,
    const float* b2, const float* g2, const float* bb2, const float* rm2, const float* rv2,
    const float* b3, const float* g3, const float* bb3, const float* rm3, const float* rv3,
    const float* fw1, const float* fb1, _Float16* ws)
{
    const int tid = threadIdx.x;
    const int rec = blockIdx.x;
    if (rec < NREC) {
        if (tid < 64) {
            const int lane = tid;
            const float* W; const float *gp = nullptr, *rvp = nullptr; int CIN, K, r2;
            if      (rec < 6)  { W = w0;  CIN = 4;  K = 3; r2 = rec;      }
            else if (rec < 12) { W = w1;  CIN = 32; K = 3; r2 = rec - 6;  gp = g0; rvp = rv0; }
            else if (rec < 22) { W = w2;  CIN = 32; K = 5; r2 = rec - 12; gp = g1; rvp = rv1; }
            else if (rec < 36) { W = w3;  CIN = 32; K = 7; r2 = rec - 22; gp = g2; rvp = rv2; }
            else               { W = fw1; CIN = 32; K = 1; r2 = 0;        gp = g3; rvp = rv3; }
            int tap = r2 >> 1, mh = r2 & 1;
            int co  = mh*16 + (lane & 15);
            int ci0 = (lane >> 4) * 8;
            half8 h;
#pragma unroll
            for (int j = 0; j < 8; ++j) {
                int ci = ci0 + j;
                float wv = (ci < CIN) ? W[(co*CIN + ci)*K + tap] : 0.0f;
                if (gp) wv *= gp[ci & 31] * rsqrtf(rvp[ci & 31] + 1e-5f);  // s_prev
                h[j] = (_Float16)wv;
            }
            *(half8*)(ws + rec*512 + lane*8) = h;
        }
    } else {
        float* fa = (float*)(ws + BN_HALFOFF);
        if (tid < 128) {
            int l = tid >> 5, co = tid & 31;
            const float *g, *bb, *rm, *rv, *bi;
            if      (l == 0) { g=g0; bb=bb0; rm=rm0; rv=rv0; bi=b0; }
            else if (l == 1) { g=g1; bb=bb1; rm=rm1; rv=rv1; bi=b1; }
            else if (l == 2) { g=g2; bb=bb2; rm=rm2; rv=rv2; bi=b2; }
            else             { g=g3; bb=bb3; rm=rm3; rv=rv3; bi=b3; }
            float s = g[co] * rsqrtf(rv[co] + 1e-5f);
            float t = bb[co] - rm[co]*s;
            float bias = bi[co];
            if      (l == 1) bias += fold_bias<3>(w1, co, g0, bb0, rm0, rv0);
            else if (l == 2) bias += fold_bias<5>(w2, co, g1, bb1, rm1, rv1);
            else if (l == 3) bias += fold_bias<7>(w3, co, g2, bb2, rm2, rv2);
            fa[(l*32 + co)*2 + 0] = bias;
            fa[(l*32 + co)*2 + 1] = -t / s;    // stored value at seq-OOB output positions
        } else if (tid < 144) {
            int hh = tid - 128;
            float acc = fb1[hh];
#pragma unroll
            for (int c = 0; c < 32; ++c) {
                float s3 = g3[c] * rsqrtf(rv3[c] + 1e-5f);
                float t3 = bb3[c] - rm3[c]*s3;
                acc += fw1[hh*32 + c] * t3;
            }
            fa[256 + hh] = acc;                // fb1'
        }
    }
}

// ---------------- layer 0: B-frags straight from global x (no staging, no LDS read) ----
// CIN=4 -> A-records zero for ci>=8, so all quads use the identical broadcast frag:
// 4 f32 loads (L1/L2-hot) + cvt, zeros in halves 4..7. Same f16 rounding point as the
// old staged path -> bit-identical output. Removes the staging loop and one barrier.
template<int DOFF>
__device__ __forceinline__ void conv_layer0(
    const _Float16* __restrict__ rec, const float2* __restrict__ bo,
    const float* __restrict__ xb, _Float16* outb, int s0, int ntb, int lane)
{
    const int q = lane >> 4, n = lane & 15;
    f32x4 acc[3][2];
#pragma unroll
    for (int nt = 0; nt < 3; ++nt)
#pragma unroll
        for (int mh = 0; mh < 2; ++mh) acc[nt][mh] = (f32x4){0.f, 0.f, 0.f, 0.f};

#pragma unroll
    for (int tap = 0; tap < 3; ++tap) {
        half8 a0 = *(const half8*)(rec + (tap*2 + 0)*512 + lane*8);
        half8 a1 = *(const half8*)(rec + (tap*2 + 1)*512 + lane*8);
#pragma unroll
        for (int nt = 0; nt < 3; ++nt) {
            int sg = s0 - 7 + (ntb + nt)*16 + n + tap;
            bool ok = (unsigned)sg < SEQ;
            float v0 = ok ? xb[0*SEQ + sg] : 0.f;
            float v1 = ok ? xb[1*SEQ + sg] : 0.f;
            float v2 = ok ? xb[2*SEQ + sg] : 0.f;
            float v3 = ok ? xb[3*SEQ + sg] : 0.f;
            half8 bf = {(_Float16)v0, (_Float16)v1, (_Float16)v2, (_Float16)v3, 0, 0, 0, 0};
            acc[nt][0] = __builtin_amdgcn_mfma_f32_16x16x32_f16(a0, bf, acc[nt][0], 0, 0, 0);
            acc[nt][1] = __builtin_amdgcn_mfma_f32_16x16x32_f16(a1, bf, acc[nt][1], 0, 0, 0);
        }
    }

#pragma unroll
    for (int nt = 0; nt < 3; ++nt) {
        int pos = (ntb + nt)*16 + n;
        bool oob = (unsigned)(s0 + DOFF + pos) >= SEQ;
#pragma unroll
        for (int mh = 0; mh < 2; ++mh) {
            int co0 = mh*16 + q*4;
            half4v hv;
#pragma unroll
            for (int r = 0; r < 4; ++r) {
                float2 p = bo[co0 + r];   // x=bias' y=oob-const
                float v = fmaxf(acc[nt][mh][r] + p.x, 0.0f);
                if (oob) v = p.y;
                hv[r] = (_Float16)v;
            }
            int cb = mh*2 + (q >> 1);
            *(half4v*)(outb + cb*CS + pos*8 + (q & 1)*4) = hv;
        }
    }
}

// ---------------- layers 1-3 via MFMA from LDS ----------------
// in/out: LDS f16, 4 chunks x rows x 8 halves (chunk cb holds ci 8cb..8cb+7).
// B-frag (lane l): pos = base+(l&15)+tap, ci = (l>>4)*8+j -> one b128 at q*CS + pos*8.
// D (C/D layout): col=lane&15 -> pos, row=q*4+r -> co (within m-half).
// Epilogue (BN folded forward): r = relu(acc + bias'); seq-OOB -> per-co const.
template<int K, int DOFF>
__device__ __forceinline__ void conv_layer(
    const _Float16* __restrict__ rec, const float2* __restrict__ bo,
    const _Float16* in, _Float16* outb, int s0, int ntb, int lane)
{
    const int q = lane >> 4, n = lane & 15;
    const _Float16* bbase = in + q*CS + (ntb*16 + n)*8;

    f32x4 acc[3][2];
#pragma unroll
    for (int nt = 0; nt < 3; ++nt)
#pragma unroll
        for (int mh = 0; mh < 2; ++mh) acc[nt][mh] = (f32x4){0.f, 0.f, 0.f, 0.f};

#pragma unroll
    for (int tap = 0; tap < K; ++tap) {
        half8 a0 = *(const half8*)(rec + (tap*2 + 0)*512 + lane*8);
        half8 a1 = *(const half8*)(rec + (tap*2 + 1)*512 + lane*8);
#pragma unroll
        for (int nt = 0; nt < 3; ++nt) {
            half8 bf = *(const half8*)(bbase + nt*128 + tap*8);
            acc[nt][0] = __builtin_amdgcn_mfma_f32_16x16x32_f16(a0, bf, acc[nt][0], 0, 0, 0);
            acc[nt][1] = __builtin_amdgcn_mfma_f32_16x16x32_f16(a1, bf, acc[nt][1], 0, 0, 0);
        }
    }

#pragma unroll
    for (int nt = 0; nt < 3; ++nt) {
        int pos = (ntb + nt)*16 + n;
        bool oob = (unsigned)(s0 + DOFF + pos) >= SEQ;
#pragma unroll
        for (int mh = 0; mh < 2; ++mh) {
            int co0 = mh*16 + q*4;
            half4v hv;
#pragma unroll
            for (int r = 0; r < 4; ++r) {
                float2 p = bo[co0 + r];   // x=bias' y=oob-const
                float v = fmaxf(acc[nt][mh][r] + p.x, 0.0f);
                if (oob) v = p.y;
                hv[r] = (_Float16)v;
            }
            int cb = mh*2 + (q >> 1);
            *(half4v*)(outb + cb*CS + pos*8 + (q & 1)*4) = hv;
        }
    }
}

extern "C" __global__ void __launch_bounds__(NTHR, 6)
dnashape_mfma(const float* __restrict__ x, const _Float16* __restrict__ ws,
              const float* __restrict__ fw2, const float* __restrict__ fb2,
              float* __restrict__ out)
{
    // Two images per block: halves barrier instances per element vs one-image blocks.
    __shared__ _Float16 bufA[2][4*CS];
    __shared__ _Float16 bufB[2][4*CS];   // 51.4 KB -> 3 blocks/CU (24 waves, 75%)

    const int tid  = threadIdx.x;
    const int tile = blockIdx.x;
    const int s0   = tile * S_TILE;
    const int b0i  = blockIdx.y * 2;

    // Zero bufA halo rows 192..199 (read beyond computed range, written by no layer).
    if (tid < 64) {
        const half8 z8 = {0,0,0,0,0,0,0,0};
        int img = tid >> 5, u = tid & 31;
        *(half8*)(&bufA[img][(u >> 3)*CS + (192 + (u & 7))*8]) = z8;
    }

    const int lane = tid & 63;
    const int wv   = uni(tid >> 6);
    const int img  = wv >> 2;               // waves 0-3 -> image 0, 4-7 -> image 1
    const int ntb  = (wv & 3) * 3;          // wave-uniform n-tile base
    const float*  fa = (const float*)(ws + BN_HALFOFF);
    const float2* bo = (const float2*)fa;

    // Buffer origins: in=s0-7, L0out=s0-6, L1out=s0-5, L2out=s0-3, L3out=s0.
    // Validity chain (valid final rows 0..179): L3 reads L2out <=185, L2 valid to 185
    // (reads L1out <=189), L1 valid to 189 (reads L0out <=191), L0 valid to 191.
    // Garbage beyond those bounds is provably never consumed.
    conv_layer0<-6>(ws + 0*512, bo + 0, x + (b0i + img)*4*SEQ, bufA[img], s0, ntb, lane);
    __syncthreads();
    conv_layer<3, -5>(ws +  6*512, bo + 32, bufA[img], bufB[img], s0, ntb, lane);
    __syncthreads();
    conv_layer<5, -3>(ws + 12*512, bo + 64, bufB[img], bufA[img], s0, ntb, lane);
    __syncthreads();
    conv_layer<7,  0>(ws + 22*512, bo + 96, bufA[img], bufB[img], s0, ntb, lane);
    __syncthreads();

    // MLP 32 -> 16 (relu) -> 1 (fw1*s3 and fb1' prefolded): one MFMA per n-tile.
    {
        const int q = lane >> 4, n = lane & 15;
        half8 am = *(const half8*)(ws + 36*512 + lane*8);
        float fb1v[4], fw2v[4];
#pragma unroll
        for (int r = 0; r < 4; ++r) { fb1v[r] = fa[256 + q*4 + r]; fw2v[r] = fw2[q*4 + r]; }
        float fb2v = fb2[0];
        const int b = b0i + img;
#pragma unroll
        for (int nt = 0; nt < 3; ++nt) {
            int pos = (ntb + nt)*16 + n;
            half8 bf = *(const half8*)(&bufB[img][q*CS + pos*8]);
            f32x4 d = {0.f, 0.f, 0.f, 0.f};
            d = __builtin_amdgcn_mfma_f32_16x16x32_f16(am, bf, d, 0, 0, 0);
            float part = 0.f;
#pragma unroll
            for (int r = 0; r < 4; ++r) part += fmaxf(d[r] + fb1v[r], 0.f)*fw2v[r];
            part += __shfl_xor(part, 16, 64);   // reduce across the 4 quads (h-blocks)
            part += __shfl_xor(part, 32, 64);
            if (lane < 16) {
                int g = s0 + pos;
                if (pos < S_TILE && g < SEQ) out[b*SEQ + g] = part + fb2v;
            }
        }
    }
}

extern "C" void kernel_launch(void* const* d_in, const int* in_sizes, int n_in,
                              void* d_out, int out_size, void* d_ws, size_t ws_size,
                              hipStream_t stream) {
    const float* p[29];
    for (int i = 0; i < 29; ++i) p[i] = (const float*)d_in[i];
    _Float16* ws = (_Float16*)d_ws;   // needs 37*1024 + 1088 = 38976 B

    prep_kernel<<<dim3(NREC + 1), 144, 0, stream>>>(
        p[1], p[7], p[13], p[19],
        p[2], p[3], p[4], p[5], p[6],
        p[8], p[9], p[10], p[11], p[12],
        p[14], p[15], p[16], p[17], p[18],
        p[20], p[21], p[22], p[23], p[24],
        p[25], p[26], ws);

    dim3 grid((SEQ + S_TILE - 1) / S_TILE, 64);   // 46 x 64, 2 images per block
    dnashape_mfma<<<grid, NTHR, 0, stream>>>(p[0], (const _Float16*)ws,
                                             p[27], p[28], (float*)d_out);
}

// Round 12
// 171.590 us; speedup vs baseline: 1.1091x; 1.0920x over previous
//
#include <hip/hip_runtime.h>

#define SEQ    8192
#define S_TILE 180            // valid output positions per tile (192 computed - 12 shrink)
#define NROW   198            // staged input rows (192 + halo 6)
#define CS     1608           // chunk stride in halves; holds 201 rows (192 + halo + pad)
#define NTHR   512            // 8 waves: waves 0-3 image 0, waves 4-7 image 1; wave owns 3 n-tiles
#define NREC   37             // 36 conv A-records + 1 MLP record (each 64 lanes x 16B = 1KB)
#define BN_HALFOFF (NREC*512) // float area offset (in halves) inside d_ws

typedef __attribute__((ext_vector_type(8))) _Float16 half8;
typedef __attribute__((ext_vector_type(4))) _Float16 half4v;
typedef __attribute__((ext_vector_type(4))) float    f32x4;

__device__ __forceinline__ int uni(int v){ return __builtin_amdgcn_readfirstlane(v); }

// Unrolled (compile-time K) bias fold: sum_ci (sum_tap W[co][ci][tap]) * t_prev[ci].
// Constant bounds -> full unroll -> independent pipelined loads (the R10 version used
// runtime K/W and serialized ~224 load-use chains ~= 20us on one wave).
template<int K>
__device__ __forceinline__ float fold_bias(const float* __restrict__ W, int co,
    const float* __restrict__ gp, const float* __restrict__ bbp,
    const float* __restrict__ rmp, const float* __restrict__ rvp)
{
    float acc = 0.f;
#pragma unroll
    for (int ci = 0; ci < 32; ++ci) {
        float sp = gp[ci] * rsqrtf(rvp[ci] + 1e-5f);
        float tp = bbp[ci] - rmp[ci]*sp;
        float wsum = 0.f;
#pragma unroll
        for (int tap = 0; tap < K; ++tap) wsum += W[(co*32 + ci)*K + tap];
        acc += wsum * tp;
    }
    return acc;
}

// ---------------- prep ----------------
// A-records carry the PREVIOUS layer's BN scale folded in: rec = W[co][ci][tap]*s_prev[ci].
// Stored activations are r = relu(z + bias'); BN applied by the next layer's folded
// weights. At seq-OOB positions store -t/s so the next layer's folded math sees 0.
// fw1 folds s3; fb1' absorbs t3. Float area: [4][32]{bias', oob_const} then fb1'[16].
// Record (tap, mh): lane l holds A[m][k] = W'[co=mh*16+(l&15)][ci=(l>>4)*8+j][tap]
// (A-operand layout for mfma_f32_16x16x32: A[m=lane&15][k=quad*8+j]).
extern "C" __global__ void prep_kernel(
    const float* w0, const float* w1, const float* w2, const float* w3,
    const float* b0, const float* g0, const float* bb0, const float* rm0, const float* rv0,
    const float* b1, const float* g1, const float* bb1, const float* rm1, const float* rv1,
    const float* b2, const float* g2, const float* bb2, const float* rm2, const float* rv2,
    const float* b3, const float* g3, const float* bb3, const float* rm3, const float* rv3,
    const float* fw1, const float* fb1, _Float16* ws)
{
    const int tid = threadIdx.x;
    const int rec = blockIdx.x;
    if (rec < NREC) {
        if (tid < 64) {
            const int lane = tid;
            const float* W; const float *gp = nullptr, *rvp = nullptr; int CIN, K, r2;
            if      (rec < 6)  { W = w0;  CIN = 4;  K = 3; r2 = rec;      }
            else if (rec < 12) { W = w1;  CIN = 32; K = 3; r2 = rec - 6;  gp = g0; rvp = rv0; }
            else if (rec < 22) { W = w2;  CIN = 32; K = 5; r2 = rec - 12; gp = g1; rvp = rv1; }
            else if (rec < 36) { W = w3;  CIN = 32; K = 7; r2 = rec - 22; gp = g2; rvp = rv2; }
            else               { W = fw1; CIN = 32; K = 1; r2 = 0;        gp = g3; rvp = rv3; }
            int tap = r2 >> 1, mh = r2 & 1;
            int co  = mh*16 + (lane & 15);
            int ci0 = (lane >> 4) * 8;
            half8 h;
#pragma unroll
            for (int j = 0; j < 8; ++j) {
                int ci = ci0 + j;
                float wv = (ci < CIN) ? W[(co*CIN + ci)*K + tap] : 0.0f;
                if (gp) wv *= gp[ci & 31] * rsqrtf(rvp[ci & 31] + 1e-5f);  // s_prev
                h[j] = (_Float16)wv;
            }
            *(half8*)(ws + rec*512 + lane*8) = h;
        }
    } else {
        float* fa = (float*)(ws + BN_HALFOFF);
        if (tid < 128) {
            int l = tid >> 5, co = tid & 31;
            const float *g, *bb, *rm, *rv, *bi;
            if      (l == 0) { g=g0; bb=bb0; rm=rm0; rv=rv0; bi=b0; }
            else if (l == 1) { g=g1; bb=bb1; rm=rm1; rv=rv1; bi=b1; }
            else if (l == 2) { g=g2; bb=bb2; rm=rm2; rv=rv2; bi=b2; }
            else             { g=g3; bb=bb3; rm=rm3; rv=rv3; bi=b3; }
            float s = g[co] * rsqrtf(rv[co] + 1e-5f);
            float t = bb[co] - rm[co]*s;
            float bias = bi[co];
            if      (l == 1) bias += fold_bias<3>(w1, co, g0, bb0, rm0, rv0);
            else if (l == 2) bias += fold_bias<5>(w2, co, g1, bb1, rm1, rv1);
            else if (l == 3) bias += fold_bias<7>(w3, co, g2, bb2, rm2, rv2);
            fa[(l*32 + co)*2 + 0] = bias;
            fa[(l*32 + co)*2 + 1] = -t / s;    // stored value at seq-OOB output positions
        } else if (tid < 144) {
            int hh = tid - 128;
            float acc = fb1[hh];
#pragma unroll
            for (int c = 0; c < 32; ++c) {
                float s3 = g3[c] * rsqrtf(rv3[c] + 1e-5f);
                float t3 = bb3[c] - rm3[c]*s3;
                acc += fw1[hh*32 + c] * t3;
            }
            fa[256 + hh] = acc;                // fb1'
        }
    }
}

// ---------------- one conv layer via MFMA ----------------
// in/out: LDS f16, 4 chunks x rows x 8 halves (chunk cb holds ci 8cb..8cb+7).
// B-frag (lane l): pos = base+(l&15)+tap, ci = (l>>4)*8+j -> one b128 at q*CS + pos*8.
// D (C/D layout): col=lane&15 -> pos, row=q*4+r -> co (within m-half).
// BC0 (layer 0): A-records zero for ci>=8 -> all quads read chunk 0 (same-address
// broadcast, conflict-free); staging never writes chunks 1-3.
// Epilogue (BN folded forward): r = relu(acc + bias'); seq-OOB -> per-co const.
template<int K, int DOFF, bool BC0>
__device__ __forceinline__ void conv_layer(
    const _Float16* __restrict__ rec, const float2* __restrict__ bo,
    const _Float16* in, _Float16* outb, int s0, int ntb, int lane)
{
    const int q = lane >> 4, n = lane & 15;
    const _Float16* bbase = in + (BC0 ? 0 : q*CS) + (ntb*16 + n)*8;

    f32x4 acc[3][2];
#pragma unroll
    for (int nt = 0; nt < 3; ++nt)
#pragma unroll
        for (int mh = 0; mh < 2; ++mh) acc[nt][mh] = (f32x4){0.f, 0.f, 0.f, 0.f};

#pragma unroll
    for (int tap = 0; tap < K; ++tap) {
        half8 a0 = *(const half8*)(rec + (tap*2 + 0)*512 + lane*8);
        half8 a1 = *(const half8*)(rec + (tap*2 + 1)*512 + lane*8);
#pragma unroll
        for (int nt = 0; nt < 3; ++nt) {
            half8 bf = *(const half8*)(bbase + nt*128 + tap*8);
            acc[nt][0] = __builtin_amdgcn_mfma_f32_16x16x32_f16(a0, bf, acc[nt][0], 0, 0, 0);
            acc[nt][1] = __builtin_amdgcn_mfma_f32_16x16x32_f16(a1, bf, acc[nt][1], 0, 0, 0);
        }
    }

#pragma unroll
    for (int nt = 0; nt < 3; ++nt) {
        int pos = (ntb + nt)*16 + n;
        bool oob = (unsigned)(s0 + DOFF + pos) >= SEQ;
#pragma unroll
        for (int mh = 0; mh < 2; ++mh) {
            int co0 = mh*16 + q*4;
            half4v hv;
#pragma unroll
            for (int r = 0; r < 4; ++r) {
                float2 p = bo[co0 + r];   // x=bias' y=oob-const
                float v = fmaxf(acc[nt][mh][r] + p.x, 0.0f);
                if (oob) v = p.y;
                hv[r] = (_Float16)v;
            }
            int cb = mh*2 + (q >> 1);
            *(half4v*)(outb + cb*CS + pos*8 + (q & 1)*4) = hv;
        }
    }
}

extern "C" __global__ void __launch_bounds__(NTHR, 6)
dnashape_mfma(const float* __restrict__ x, const _Float16* __restrict__ ws,
              const float* __restrict__ fw2, const float* __restrict__ fb2,
              float* __restrict__ out)
{
    // Two images per block: halves barrier instances per element vs one-image blocks.
    __shared__ _Float16 bufA[2][4*CS];
    __shared__ _Float16 bufB[2][4*CS];   // 51.4 KB -> 3 blocks/CU (24 waves, 75%)

    const int tid  = threadIdx.x;
    const int tile = blockIdx.x;
    const int s0   = tile * S_TILE;
    const int b0i  = blockIdx.y * 2;

    // Stage both images' chunk 0: f16(x[ci 0..3]) + 4 zero-halves (threads 0-255 -> img 0).
    // L0 reads it via the BC0 broadcast path; chunks 1-3 never touched.
    const int timg = tid >> 8;
    {
        const float* xb = x + (b0i + timg)*4*SEQ;
        for (int li = (tid & 255); li < NROW; li += 256) {
            int sg = s0 - 7 + li;   // input origin s0-7 (halo 7)
            bool ok = (unsigned)sg < SEQ;
            float v0 = ok ? xb[0*SEQ + sg] : 0.f;
            float v1 = ok ? xb[1*SEQ + sg] : 0.f;
            float v2 = ok ? xb[2*SEQ + sg] : 0.f;
            float v3 = ok ? xb[3*SEQ + sg] : 0.f;
            half8 h0 = {(_Float16)v0, (_Float16)v1, (_Float16)v2, (_Float16)v3, 0, 0, 0, 0};
            *(half8*)(&bufB[timg][0*CS + li*8]) = h0;
        }
        // Zero bufA halo rows 192..199 (read beyond computed range, written by none).
        const half8 z8 = {0,0,0,0,0,0,0,0};
        int u = tid & 255;
        if (u < 32) *(half8*)(&bufA[timg][(u >> 3)*CS + (192 + (u & 7))*8]) = z8;
    }
    __syncthreads();

    const int lane = tid & 63;
    const int wv   = uni(tid >> 6);
    const int img  = wv >> 2;               // waves 0-3 -> image 0, 4-7 -> image 1
    const int ntb  = (wv & 3) * 3;          // wave-uniform n-tile base
    const float*  fa = (const float*)(ws + BN_HALFOFF);
    const float2* bo = (const float2*)fa;

    // Buffer origins: in=s0-7, L0out=s0-6, L1out=s0-5, L2out=s0-3, L3out=s0.
    // Validity chain (valid final rows 0..179): L3 reads L2out <=185, L2 valid to 185
    // (reads L1out <=189), L1 valid to 189 (reads L0out <=191), L0 valid to 191
    // (reads staged <=193 < 198). Garbage beyond is provably never consumed.
    conv_layer<3, -6, true >(ws +  0*512, bo +  0, bufB[img], bufA[img], s0, ntb, lane);
    __syncthreads();
    conv_layer<3, -5, false>(ws +  6*512, bo + 32, bufA[img], bufB[img], s0, ntb, lane);
    __syncthreads();
    conv_layer<5, -3, false>(ws + 12*512, bo + 64, bufB[img], bufA[img], s0, ntb, lane);
    __syncthreads();
    conv_layer<7,  0, false>(ws + 22*512, bo + 96, bufA[img], bufB[img], s0, ntb, lane);
    __syncthreads();

    // MLP 32 -> 16 (relu) -> 1 (fw1*s3 and fb1' prefolded): one MFMA per n-tile.
    {
        const int q = lane >> 4, n = lane & 15;
        half8 am = *(const half8*)(ws + 36*512 + lane*8);
        float fb1v[4], fw2v[4];
#pragma unroll
        for (int r = 0; r < 4; ++r) { fb1v[r] = fa[256 + q*4 + r]; fw2v[r] = fw2[q*4 + r]; }
        float fb2v = fb2[0];
        const int b = b0i + img;
#pragma unroll
        for (int nt = 0; nt < 3; ++nt) {
            int pos = (ntb + nt)*16 + n;
            half8 bf = *(const half8*)(&bufB[img][q*CS + pos*8]);
            f32x4 d = {0.f, 0.f, 0.f, 0.f};
            d = __builtin_amdgcn_mfma_f32_16x16x32_f16(am, bf, d, 0, 0, 0);
            float part = 0.f;
#pragma unroll
            for (int r = 0; r < 4; ++r) part += fmaxf(d[r] + fb1v[r], 0.f)*fw2v[r];
            part += __shfl_xor(part, 16, 64);   // reduce across the 4 quads (h-blocks)
            part += __shfl_xor(part, 32, 64);
            if (lane < 16) {
                int g = s0 + pos;
                if (pos < S_TILE && g < SEQ) out[b*SEQ + g] = part + fb2v;
            }
        }
    }
}

extern "C" void kernel_launch(void* const* d_in, const int* in_sizes, int n_in,
                              void* d_out, int out_size, void* d_ws, size_t ws_size,
                              hipStream_t stream) {
    const float* p[29];
    for (int i = 0; i < 29; ++i) p[i] = (const float*)d_in[i];
    _Float16* ws = (_Float16*)d_ws;   // needs 37*1024 + 1088 = 38976 B

    prep_kernel<<<dim3(NREC + 1), 144, 0, stream>>>(
        p[1], p[7], p[13], p[19],
        p[2], p[3], p[4], p[5], p[6],
        p[8], p[9], p[10], p[11], p[12],
        p[14], p[15], p[16], p[17], p[18],
        p[20], p[21], p[22], p[23], p[24],
        p[25], p[26], ws);

    dim3 grid((SEQ + S_TILE - 1) / S_TILE, 64);   // 46 x 64, 2 images per block
    dnashape_mfma<<<grid, NTHR, 0, stream>>>(p[0], (const _Float16*)ws,
                                             p[27], p[28], (float*)d_out);
}